// Round 11
// baseline (85.741 us; speedup 1.0000x reference)
//
#include <hip/hip_runtime.h>

typedef float v4f __attribute__((ext_vector_type(4)));
typedef short v8s __attribute__((ext_vector_type(8)));

#define BM 64

__device__ __forceinline__ unsigned short f2bf(float f) {
    union { float f; unsigned u; } v; v.f = f;
    unsigned u = v.u;
    u += 0x7FFFu + ((u >> 16) & 1u);   // round-to-nearest-even
    return (unsigned short)(u >> 16);
}

// pack two f32 -> two bf16 (RNE) in one instruction
__device__ __forceinline__ unsigned cvt_pk_bf16(float lo, float hi) {
    unsigned r;
    asm("v_cvt_pk_bf16_f32 %0, %1, %2" : "=v"(r) : "v"(lo), "v"(hi));
    return r;
}

// async global->LDS, 16B per lane; LDS dest is WAVE-UNIFORM base + lane*16
__device__ __forceinline__ void gload_lds16(const unsigned short* g, unsigned short* l) {
    __builtin_amdgcn_global_load_lds(
        (const __attribute__((address_space(1))) void*)(const void*)g,
        (__attribute__((address_space(3))) void*)(void*)l,
        16, 0, 0);
}

// counted vmcnt wait with literal immediate; "memory" pins issue order so the
// issued-after accounting below matches the emitted code.
#define VMW(N) asm volatile("s_waitcnt vmcnt(" #N ")" ::: "memory")

// shared-LDS sync WITHOUT draining vmcnt (ds ops are lgkm-tracked)
#define LDS_BARRIER() do {                                        \
    asm volatile("s_waitcnt lgkmcnt(0)" ::: "memory");            \
    __builtin_amdgcn_s_barrier();                                 \
    __builtin_amdgcn_sched_barrier(0);                            \
} while (0)

__device__ __forceinline__ float fast_exp2(float x) {
#if __has_builtin(__builtin_amdgcn_exp2f)
    return __builtin_amdgcn_exp2f(x);
#else
    return exp2f(x);
#endif
}
__device__ __forceinline__ float fast_rcp(float x) {
#if __has_builtin(__builtin_amdgcn_rcpf)
    return __builtin_amdgcn_rcpf(x);
#else
    return 1.0f / x;
#endif
}
__device__ __forceinline__ float fast_tanh(float y) {
    float t = fast_exp2(y * 2.885390081777927f);
    return (t - 1.0f) * fast_rcp(t + 1.0f);
}
__device__ __forceinline__ float fast_sigmoid(float z) {
    float t = fast_exp2(-1.4426950408889634f * z);
    return fast_rcp(1.0f + t);
}

// ---------------------------------------------------------------------------
// Pack 5 weight matrices (fp32 row-major [N][K]) into bf16 MFMA-B-fragment
// order (canonical 16x32 tile: lane = ((k>>3)&3)*16 + (n&15), j = k&7).
// ws layout: Wb(98304) | W1(65536) | W2 | Wa | Wt   (bf16 elems)
// ---------------------------------------------------------------------------
__global__ void prep_pack(const float* __restrict__ Wb, const float* __restrict__ W1,
                          const float* __restrict__ W2, const float* __restrict__ Wa,
                          const float* __restrict__ Wt, unsigned short* __restrict__ ws)
{
    int e = blockIdx.x * 256 + threadIdx.x;
    if (e >= 360448) return;
    const float* src; int K; int base;
    if (e < 98304)       { src = Wb; K = 384; base = 0; }
    else if (e < 163840) { src = W1; K = 256; base = 98304; }
    else if (e < 229376) { src = W2; K = 256; base = 163840; }
    else if (e < 294912) { src = Wa; K = 256; base = 229376; }
    else                 { src = Wt; K = 256; base = 294912; }
    int le   = e - base;
    int j    = le & 7;
    int lane = (le >> 3) & 63;
    int tile = le >> 9;
    int kt   = K >> 5;
    int ks   = tile % kt;
    int nt   = tile / kt;
    int n = nt * 16 + (lane & 15);
    int k = ks * 32 + (lane >> 4) * 8 + j;
    ws[e] = f2bf(src[n * K + k]);
}

// ---------------------------------------------------------------------------
// Fused CfC cell, BM=64 rows/block, 4 waves each owning 64 output cols.
// Weight stream: global_load_lds -> 3 wave-private 16KB buffers, ahead-2,
// EXACT issued-after vmcnt counting (never waits on input loads / stores).
// Phase 2 holds ALL 32 A-fragments in registers (loaded once) -> per step
// only 4 B ds_reads; g and ks fully unrolled (static indices everywhere).
// LDS 80KB: X/input [0,32KB) + wbuf[3] at 32/48/64KB. 2 blocks/CU.
// ---------------------------------------------------------------------------
__global__ __launch_bounds__(256, 2) void cfc_fused(
    const float* __restrict__ xin, const float* __restrict__ hx,
    const float* __restrict__ ts,
    const float* __restrict__ bb, const float* __restrict__ b1,
    const float* __restrict__ b2, const float* __restrict__ ba,
    const float* __restrict__ bt,
    const unsigned short* __restrict__ wpk,
    float* __restrict__ out)
{
    __shared__ unsigned short lds[40960];   // 80 KB
    const int tid  = threadIdx.x;
    const int lane = tid & 63;
    const int w    = tid >> 6;        // wave id = output-col group (64 cols)
    const int row0 = blockIdx.x * BM;

    // stage weight tile for flat step s into wbuf[s%3] (4KB per wave)
    auto STAGE = [&](int s) {
        unsigned short* wb = &lds[16384 + (s % 3) * 8192 + w * 2048];
        #pragma unroll
        for (int i = 0; i < 4; ++i) {
            size_t goff;
            if (s < 12) {                       // phase 1: Wb, i = nt
                goff = (size_t)((w * 4 + i) * 12 + s) * 512;
            } else {                            // phase 2: W1/W2/Wa/Wt, i = mat
                int s2 = s - 12, g = s2 >> 3, ks = s2 & 7;
                goff = 98304u + (size_t)i * 65536
                     + (size_t)((w * 4 + g) * 8 + ks) * 512;
            }
            gload_lds16(wpk + goff + (size_t)lane * 8, wb + i * 512);
        }
    };

#define ISSUE_IN(SRC, LD, BUF) do {                                           \
    _Pragma("unroll")                                                         \
    for (int it = 0; it < 8; ++it) {                                          \
        int i_ = tid + it * 256; int r_ = i_ >> 5; int c4_ = i_ & 31;         \
        BUF[it] = *(reinterpret_cast<const v4f*>((SRC) + (size_t)r_ * (LD)) + c4_); \
    }                                                                         \
} while (0)

#define WRITE_IN(BUF) do {                                                    \
    _Pragma("unroll")                                                         \
    for (int it = 0; it < 8; ++it) {                                          \
        int i_ = tid + it * 256; int r_ = i_ >> 5; int c4_ = i_ & 31;         \
        uint2 pk_;                                                            \
        pk_.x = cvt_pk_bf16(BUF[it][0], BUF[it][1]);                          \
        pk_.y = cvt_pk_bf16(BUF[it][2], BUF[it][3]);                          \
        int idx_ = (((r_ >> 4) * 4 + (c4_ >> 3)) * 64 + ((c4_ >> 1) & 3) * 16 \
                    + (r_ & 15)) * 8 + (c4_ & 1) * 4;                         \
        *reinterpret_cast<uint2*>(&lds[idx_]) = pk_;                          \
    }                                                                         \
} while (0)

// phase-1 step S (0..11): A-reads issued before the counted wait
#define P1STEP(S, N) do {                                                     \
    STAGE((S) + 2);                                                           \
    v8s aa_[4];                                                               \
    _Pragma("unroll")                                                         \
    for (int mt = 0; mt < 4; ++mt)                                            \
        aa_[mt] = *reinterpret_cast<const v8s*>(                              \
                      &lds[((mt * 4 + ((S) & 3)) * 64 + lane) * 8]);          \
    VMW(N);                                                                   \
    const unsigned short* wb_ = &lds[16384 + ((S) % 3) * 8192 + w * 2048];    \
    v8s bf_[4];                                                               \
    _Pragma("unroll")                                                         \
    for (int nt = 0; nt < 4; ++nt)                                            \
        bf_[nt] = *reinterpret_cast<const v8s*>(wb_ + nt * 512 + lane * 8);   \
    __builtin_amdgcn_s_setprio(1);                                            \
    _Pragma("unroll")                                                         \
    for (int nt = 0; nt < 4; ++nt)                                            \
        _Pragma("unroll")                                                     \
        for (int mt = 0; mt < 4; ++mt)                                        \
            acc[nt][mt] = __builtin_amdgcn_mfma_f32_16x16x32_bf16(            \
                              aa_[mt], bf_[nt], acc[nt][mt], 0, 0, 0);        \
    __builtin_amdgcn_s_setprio(0);                                            \
} while (0)

// phase-2 step: flat S, k-slice KS, counted wait N; A from registers
#define P2BODY(S, KS, N) do {                                                 \
    VMW(N);                                                                   \
    const unsigned short* wb_ = &lds[16384 + ((S) % 3) * 8192 + w * 2048];    \
    v8s bf_[4];                                                               \
    _Pragma("unroll")                                                         \
    for (int mat = 0; mat < 4; ++mat)                                         \
        bf_[mat] = *reinterpret_cast<const v8s*>(wb_ + mat * 512 + lane * 8); \
    __builtin_amdgcn_s_setprio(1);                                            \
    _Pragma("unroll")                                                         \
    for (int mat = 0; mat < 4; ++mat)                                         \
        _Pragma("unroll")                                                     \
        for (int mt = 0; mt < 4; ++mt)                                        \
            a2[mat][mt] = __builtin_amdgcn_mfma_f32_16x16x32_bf16(            \
                              afr[mt][(KS)], bf_[mat], a2[mat][mt], 0, 0, 0); \
    __builtin_amdgcn_s_setprio(0);                                            \
} while (0)

#define P2STEP(S, KS, N)    do { STAGE((S) + 2); P2BODY(S, KS, N); } while (0)
#define P2STEP_NS(S, KS, N) do { P2BODY(S, KS, N); } while (0)

#define GINIT(G) do {                                                         \
    const int n_ = w * 64 + (G) * 16 + (lane & 15);                           \
    float v1_ = b1[n_], v2_ = b2[n_], va_ = ba[n_], vt_ = bt[n_];             \
    v4f q1_ = {v1_,v1_,v1_,v1_}, q2_ = {v2_,v2_,v2_,v2_};                     \
    v4f qa_ = {va_,va_,va_,va_}, qt_ = {vt_,vt_,vt_,vt_};                     \
    _Pragma("unroll")                                                         \
    for (int mt = 0; mt < 4; ++mt) {                                          \
        a2[0][mt] = q1_; a2[1][mt] = q2_; a2[2][mt] = qa_; a2[3][mt] = qt_;   \
    }                                                                         \
} while (0)

#define EPI(G) do {                                                           \
    const int n_ = w * 64 + (G) * 16 + (lane & 15);                           \
    _Pragma("unroll")                                                         \
    for (int mt = 0; mt < 4; ++mt) {                                          \
        int rowb_ = row0 + mt * 16 + ((lane >> 4) << 2);                      \
        _Pragma("unroll")                                                     \
        for (int r = 0; r < 4; ++r) {                                         \
            float ff1_ = fast_tanh(a2[0][mt][r]);                             \
            float ff2_ = fast_tanh(a2[1][mt][r]);                             \
            float ti_  = fast_sigmoid(a2[2][mt][r] * tsv4[mt][r] + a2[3][mt][r]); \
            out[(size_t)(rowb_ + r) * 256 + n_] = ff1_ + ti_ * (ff2_ - ff1_); \
        }                                                                     \
    }                                                                         \
} while (0)

    STAGE(0); STAGE(1);                 // weight pipeline ahead-2

    // ---------------- phase 1: backbone GEMM, acc[nt][mt] -------------------
    v4f acc[4][4];
    #pragma unroll
    for (int nt = 0; nt < 4; ++nt) {
        float bv = bb[w * 64 + nt * 16 + (lane & 15)];
        v4f bvv = {bv, bv, bv, bv};
        #pragma unroll
        for (int mt = 0; mt < 4; ++mt) acc[nt][mt] = bvv;
    }

    v4f stgA[8], stgB[8];
    // chunk 0: in[0:128]
    ISSUE_IN(xin + (size_t)row0 * 128, 128, stgA);
    VMW(0);                              // kernel start: nothing to overlap
    WRITE_IN(stgA);
    ISSUE_IN(hx + (size_t)row0 * 256, 256, stgB);        // prefetch chunk 1
    LDS_BARRIER();
    P1STEP(0, 16); P1STEP(1, 16); P1STEP(2, 8); P1STEP(3, 8);
    // chunk 1: hx[0:128]
    LDS_BARRIER();
    VMW(16);                             // in1 done (st2..st5 newer)
    WRITE_IN(stgB);
    ISSUE_IN(hx + (size_t)row0 * 256 + 128, 256, stgA);  // prefetch chunk 2
    LDS_BARRIER();
    P1STEP(4, 16); P1STEP(5, 16); P1STEP(6, 8); P1STEP(7, 8);
    // chunk 2: hx[128:256]
    LDS_BARRIER();
    VMW(16);                             // in2 done (st6..st9 newer)
    WRITE_IN(stgA);
    LDS_BARRIER();
    P1STEP(8, 8); P1STEP(9, 8); P1STEP(10, 8); P1STEP(11, 8);

    // hoist ts as 4x v4f (rows rowb..rowb+3 contiguous, 16B aligned)
    v4f tsv4[4];
    #pragma unroll
    for (int mt = 0; mt < 4; ++mt)
        tsv4[mt] = *reinterpret_cast<const v4f*>(
                       &ts[row0 + mt * 16 + ((lane >> 4) << 2)]);

    LDS_BARRIER();                  // all waves done reading last input chunk

    // ------------- activation + write X to LDS in packed A-frag layout ------
    #pragma unroll
    for (int nt = 0; nt < 4; ++nt)
        #pragma unroll
        for (int mt = 0; mt < 4; ++mt)
            #pragma unroll
            for (int r = 0; r < 4; ++r) {
                float xv = 1.7159f * fast_tanh(0.666f * acc[nt][mt][r]);
                int idx = ((mt*8 + w*2 + (nt >> 1)) * 64
                           + ((nt & 1)*2 + ((lane >> 3) & 1)) * 16 + (lane >> 4)*4 + r) * 8
                          + (lane & 7);
                lds[idx] = f2bf(xv);
            }
    LDS_BARRIER();                  // X visible to all waves

    // ---- load ALL 32 phase-2 A-fragments into registers (one time) --------
    v8s afr[4][8];
    #pragma unroll
    for (int mt = 0; mt < 4; ++mt)
        #pragma unroll
        for (int ks = 0; ks < 8; ++ks)
            afr[mt][ks] = *reinterpret_cast<const v8s*>(
                              &lds[((mt * 8 + ks) * 64 + lane) * 8]);

    // ---------------- phase 2: 4 GEMMs over X + fused epilogue --------------
    v4f a2[4][4];
    // g0 (vmcnt: after st12 came st13+ts4+bias4+st14 = 16; after st13: 16)
    GINIT(0);
    P2STEP(12,0,16); P2STEP(13,1,16); P2STEP(14,2,8); P2STEP(15,3,8);
    P2STEP(16,4,8);  P2STEP(17,5,8);  P2STEP(18,6,8); P2STEP(19,7,8);
    EPI(0);
    // g1 (after stage(s): 1 stage + 16 stores + 4 bias + 1 stage = 28)
    GINIT(1);
    P2STEP(20,0,28); P2STEP(21,1,28); P2STEP(22,2,8); P2STEP(23,3,8);
    P2STEP(24,4,8);  P2STEP(25,5,8);  P2STEP(26,6,8); P2STEP(27,7,8);
    EPI(1);
    // g2
    GINIT(2);
    P2STEP(28,0,28); P2STEP(29,1,28); P2STEP(30,2,8); P2STEP(31,3,8);
    P2STEP(32,4,8);  P2STEP(33,5,8);  P2STEP(34,6,8); P2STEP(35,7,8);
    EPI(2);
    // g3 (tail: st43 is the last stage, issued at s=41)
    GINIT(3);
    P2STEP(36,0,28); P2STEP(37,1,28); P2STEP(38,2,8); P2STEP(39,3,8);
    P2STEP(40,4,8);  P2STEP(41,5,8);  P2STEP_NS(42,6,4); P2STEP_NS(43,7,0);
    EPI(3);

#undef ISSUE_IN
#undef WRITE_IN
#undef P1STEP
#undef P2BODY
#undef P2STEP
#undef P2STEP_NS
#undef GINIT
#undef EPI
}

extern "C" void kernel_launch(void* const* d_in, const int* in_sizes, int n_in,
                              void* d_out, int out_size, void* d_ws, size_t ws_size,
                              hipStream_t stream)
{
    const float* xin = (const float*)d_in[0];
    const float* hx  = (const float*)d_in[1];
    const float* ts  = (const float*)d_in[2];
    const float* Wb  = (const float*)d_in[3];
    const float* bb  = (const float*)d_in[4];
    const float* W1  = (const float*)d_in[5];
    const float* b1  = (const float*)d_in[6];
    const float* W2  = (const float*)d_in[7];
    const float* b2  = (const float*)d_in[8];
    const float* Wa  = (const float*)d_in[9];
    const float* ba  = (const float*)d_in[10];
    const float* Wt  = (const float*)d_in[11];
    const float* bt  = (const float*)d_in[12];

    if (ws_size < 360448 * sizeof(unsigned short)) return;
    unsigned short* wpk = (unsigned short*)d_ws;

    prep_pack<<<1408, 256, 0, stream>>>(Wb, W1, W2, Wa, Wt, wpk);
    cfc_fused<<<1024, 256, 0, stream>>>(xin, hx, ts, bb, b1, b2, ba, bt, wpk,
                                        (float*)d_out);
}

// Round 12
// 75.864 us; speedup vs baseline: 1.1302x; 1.1302x over previous
//
#include <hip/hip_runtime.h>

typedef float v4f __attribute__((ext_vector_type(4)));
typedef short v8s __attribute__((ext_vector_type(8)));

#define BM 64

__device__ __forceinline__ unsigned short f2bf(float f) {
    union { float f; unsigned u; } v; v.f = f;
    unsigned u = v.u;
    u += 0x7FFFu + ((u >> 16) & 1u);   // round-to-nearest-even
    return (unsigned short)(u >> 16);
}

// pack two f32 -> two bf16 (RNE) in one instruction
__device__ __forceinline__ unsigned cvt_pk_bf16(float lo, float hi) {
    unsigned r;
    asm("v_cvt_pk_bf16_f32 %0, %1, %2" : "=v"(r) : "v"(lo), "v"(hi));
    return r;
}

// shared-LDS sync WITHOUT draining vmcnt: only lgkm (ds ops) must complete;
// in-flight global loads into registers survive the barrier.
#define LDS_BARRIER() do {                                        \
    asm volatile("s_waitcnt lgkmcnt(0)" ::: "memory");            \
    __builtin_amdgcn_s_barrier();                                 \
    __builtin_amdgcn_sched_barrier(0);                            \
} while (0)

#define SB() __builtin_amdgcn_sched_barrier(0)

__device__ __forceinline__ float fast_exp2(float x) {
#if __has_builtin(__builtin_amdgcn_exp2f)
    return __builtin_amdgcn_exp2f(x);
#else
    return exp2f(x);
#endif
}
__device__ __forceinline__ float fast_rcp(float x) {
#if __has_builtin(__builtin_amdgcn_rcpf)
    return __builtin_amdgcn_rcpf(x);
#else
    return 1.0f / x;
#endif
}
__device__ __forceinline__ float fast_tanh(float y) {
    float t = fast_exp2(y * 2.885390081777927f);
    return (t - 1.0f) * fast_rcp(t + 1.0f);
}
__device__ __forceinline__ float fast_sigmoid(float z) {
    float t = fast_exp2(-1.4426950408889634f * z);
    return fast_rcp(1.0f + t);
}

// ---------------------------------------------------------------------------
// Pack 5 weight matrices (fp32 row-major [N][K]) into bf16 MFMA-B-fragment
// order (canonical 16x32 tile: lane = ((k>>3)&3)*16 + (n&15), j = k&7).
// ws layout: Wb(98304) | W1(65536) | W2 | Wa | Wt   (bf16 elems)
// ---------------------------------------------------------------------------
__global__ void prep_pack(const float* __restrict__ Wb, const float* __restrict__ W1,
                          const float* __restrict__ W2, const float* __restrict__ Wa,
                          const float* __restrict__ Wt, unsigned short* __restrict__ ws)
{
    int e = blockIdx.x * 256 + threadIdx.x;
    if (e >= 360448) return;
    const float* src; int K; int base;
    if (e < 98304)       { src = Wb; K = 384; base = 0; }
    else if (e < 163840) { src = W1; K = 256; base = 98304; }
    else if (e < 229376) { src = W2; K = 256; base = 163840; }
    else if (e < 294912) { src = Wa; K = 256; base = 229376; }
    else                 { src = Wt; K = 256; base = 294912; }
    int le   = e - base;
    int j    = le & 7;
    int lane = (le >> 3) & 63;
    int tile = le >> 9;
    int kt   = K >> 5;
    int ks   = tile % kt;
    int nt   = tile / kt;
    int n = nt * 16 + (lane & 15);
    int k = ks * 32 + (lane >> 4) * 8 + j;
    ws[e] = f2bf(src[n * K + k]);
}

// ---------------------------------------------------------------------------
// Fused CfC cell, BM=64 rows/block, 4 waves each owning 64 output cols.
// Weights NEVER touch LDS: per-wave B-tiles load straight into a 3-deep
// register rotation br0/br1/br2 (issue step s+2 while computing step s;
// 2 full steps in flight cover L2 latency). All 44 flat steps statically
// unrolled; waitcnt left to the compiler's exact per-register accounting.
// Phase-2 A-fragments (from X in LDS) prefetched 1 step ahead (afA/afB).
// LDS 32KB = input-chunk/X only; lgkm-only barriers; sched_barrier(0) per
// step bounds scheduler motion (anti-clumping). 2 blocks/CU at (256,2).
// ---------------------------------------------------------------------------
__global__ __launch_bounds__(256, 2) void cfc_fused(
    const float* __restrict__ xin, const float* __restrict__ hx,
    const float* __restrict__ ts,
    const float* __restrict__ bb, const float* __restrict__ b1,
    const float* __restrict__ b2, const float* __restrict__ ba,
    const float* __restrict__ bt,
    const unsigned short* __restrict__ wpk,
    float* __restrict__ out)
{
    __shared__ unsigned short lds[16384];   // 32 KB: chunk [0,8K) / X [0,16K)
    const int tid  = threadIdx.x;
    const int lane = tid & 63;
    const int w    = tid >> 6;        // wave id = output-col group (64 cols)
    const int row0 = blockIdx.x * BM;

    v8s br0[4], br1[4], br2[4];       // 3-deep B rotation (48 VGPR)
    v8s afA[4], afB[4];               // phase-2 A double buffer (32 VGPR)

// load step-S weight tile (4 x 16B/lane, coalesced) into DST regs
#define BLOAD(S, DST) do {                                                    \
    _Pragma("unroll")                                                         \
    for (int i = 0; i < 4; ++i) {                                             \
        size_t goff;                                                          \
        if ((S) < 12) {                                                       \
            goff = (size_t)((w * 4 + i) * 12 + (S)) * 512;                    \
        } else {                                                              \
            int s2_ = (S) - 12, g_ = s2_ >> 3, ks_ = s2_ & 7;                 \
            goff = 98304u + (size_t)i * 65536                                 \
                 + (size_t)((w * 4 + g_) * 8 + ks_) * 512;                    \
        }                                                                     \
        DST[i] = *reinterpret_cast<const v8s*>(wpk + goff + (size_t)lane * 8);\
    }                                                                         \
} while (0)

#define ISSUE_IN(SRC, LD, BUF) do {                                           \
    _Pragma("unroll")                                                         \
    for (int it = 0; it < 8; ++it) {                                          \
        int i_ = tid + it * 256; int r_ = i_ >> 5; int c4_ = i_ & 31;         \
        BUF[it] = *(reinterpret_cast<const v4f*>((SRC) + (size_t)r_ * (LD)) + c4_); \
    }                                                                         \
} while (0)

#define WRITE_IN(BUF) do {                                                    \
    _Pragma("unroll")                                                         \
    for (int it = 0; it < 8; ++it) {                                          \
        int i_ = tid + it * 256; int r_ = i_ >> 5; int c4_ = i_ & 31;         \
        uint2 pk_;                                                            \
        pk_.x = cvt_pk_bf16(BUF[it][0], BUF[it][1]);                          \
        pk_.y = cvt_pk_bf16(BUF[it][2], BUF[it][3]);                          \
        int idx_ = (((r_ >> 4) * 4 + (c4_ >> 3)) * 64 + ((c4_ >> 1) & 3) * 16 \
                    + (r_ & 15)) * 8 + (c4_ & 1) * 4;                         \
        *reinterpret_cast<uint2*>(&lds[idx_]) = pk_;                          \
    }                                                                         \
} while (0)

// phase-1 step: A in-step from chunk LDS, B from CUR regs, prefetch PRE
#define P1STEP(S, CUR, PRE) do {                                              \
    BLOAD((S) + 2, PRE);                                                      \
    v8s aa_[4];                                                               \
    _Pragma("unroll")                                                         \
    for (int mt = 0; mt < 4; ++mt)                                            \
        aa_[mt] = *reinterpret_cast<const v8s*>(                              \
                      &lds[((mt * 4 + ((S) & 3)) * 64 + lane) * 8]);          \
    __builtin_amdgcn_s_setprio(1);                                            \
    _Pragma("unroll")                                                         \
    for (int nt = 0; nt < 4; ++nt)                                            \
        _Pragma("unroll")                                                     \
        for (int mt = 0; mt < 4; ++mt)                                        \
            acc[nt][mt] = __builtin_amdgcn_mfma_f32_16x16x32_bf16(            \
                              aa_[mt], CUR[nt], acc[nt][mt], 0, 0, 0);        \
    __builtin_amdgcn_s_setprio(0);                                            \
    SB();                                                                     \
} while (0)

// phase-2 step: A from AC regs (prefetched last step), prefetch A[KS+1]->AP,
// B from CUR regs, prefetch weight tile S+2 -> PRE
#define P2STEP(S, KS, CUR, PRE, AC, AP) do {                                  \
    BLOAD((S) + 2, PRE);                                                      \
    _Pragma("unroll")                                                         \
    for (int mt = 0; mt < 4; ++mt)                                            \
        AP[mt] = *reinterpret_cast<const v8s*>(                               \
                     &lds[((mt * 8 + (((KS) + 1) & 7)) * 64 + lane) * 8]);    \
    __builtin_amdgcn_s_setprio(1);                                            \
    _Pragma("unroll")                                                         \
    for (int mat = 0; mat < 4; ++mat)                                         \
        _Pragma("unroll")                                                     \
        for (int mt = 0; mt < 4; ++mt)                                        \
            a2[mat][mt] = __builtin_amdgcn_mfma_f32_16x16x32_bf16(            \
                              AC[mt], CUR[mat], a2[mat][mt], 0, 0, 0);        \
    __builtin_amdgcn_s_setprio(0);                                            \
    SB();                                                                     \
} while (0)

// tail variant: no weight prefetch
#define P2STEP_NS(S, KS, CUR, AC, AP) do {                                    \
    _Pragma("unroll")                                                         \
    for (int mt = 0; mt < 4; ++mt)                                            \
        AP[mt] = *reinterpret_cast<const v8s*>(                               \
                     &lds[((mt * 8 + (((KS) + 1) & 7)) * 64 + lane) * 8]);    \
    __builtin_amdgcn_s_setprio(1);                                            \
    _Pragma("unroll")                                                         \
    for (int mat = 0; mat < 4; ++mat)                                         \
        _Pragma("unroll")                                                     \
        for (int mt = 0; mt < 4; ++mt)                                        \
            a2[mat][mt] = __builtin_amdgcn_mfma_f32_16x16x32_bf16(            \
                              AC[mt], CUR[mat], a2[mat][mt], 0, 0, 0);        \
    __builtin_amdgcn_s_setprio(0);                                            \
    SB();                                                                     \
} while (0)

#define GINIT(G) do {                                                         \
    const int n_ = w * 64 + (G) * 16 + (lane & 15);                           \
    float v1_ = b1[n_], v2_ = b2[n_], va_ = ba[n_], vt_ = bt[n_];             \
    v4f q1_ = {v1_,v1_,v1_,v1_}, q2_ = {v2_,v2_,v2_,v2_};                     \
    v4f qa_ = {va_,va_,va_,va_}, qt_ = {vt_,vt_,vt_,vt_};                     \
    _Pragma("unroll")                                                         \
    for (int mt = 0; mt < 4; ++mt) {                                          \
        a2[0][mt] = q1_; a2[1][mt] = q2_; a2[2][mt] = qa_; a2[3][mt] = qt_;   \
    }                                                                         \
} while (0)

#define EPI(G) do {                                                           \
    const int n_ = w * 64 + (G) * 16 + (lane & 15);                           \
    _Pragma("unroll")                                                         \
    for (int mt = 0; mt < 4; ++mt) {                                          \
        int rowb_ = row0 + mt * 16 + ((lane >> 4) << 2);                      \
        _Pragma("unroll")                                                     \
        for (int r = 0; r < 4; ++r) {                                         \
            float ff1_ = fast_tanh(a2[0][mt][r]);                             \
            float ff2_ = fast_tanh(a2[1][mt][r]);                             \
            float ti_  = fast_sigmoid(a2[2][mt][r] * tsv4[mt][r] + a2[3][mt][r]); \
            out[(size_t)(rowb_ + r) * 256 + n_] = ff1_ + ti_ * (ff2_ - ff1_); \
        }                                                                     \
    }                                                                         \
} while (0)

    BLOAD(0, br0); BLOAD(1, br1);       // weight pipeline: 2 tiles in flight

    // ---------------- phase 1: backbone GEMM, acc[nt][mt] -------------------
    v4f acc[4][4];
    #pragma unroll
    for (int nt = 0; nt < 4; ++nt) {
        float bv = bb[w * 64 + nt * 16 + (lane & 15)];
        v4f bvv = {bv, bv, bv, bv};
        #pragma unroll
        for (int mt = 0; mt < 4; ++mt) acc[nt][mt] = bvv;
    }

    v4f stgA[8], stgB[8];
    // chunk 0: in[0:128]
    ISSUE_IN(xin + (size_t)row0 * 128, 128, stgA);
    WRITE_IN(stgA);                                      // waits stgA only
    ISSUE_IN(hx + (size_t)row0 * 256, 256, stgB);        // prefetch chunk 1
    LDS_BARRIER();
    P1STEP(0, br0, br2); P1STEP(1, br1, br0);
    P1STEP(2, br2, br1); P1STEP(3, br0, br2);
    // chunk 1: hx[0:128]
    LDS_BARRIER();                       // all waves done with chunk 0
    WRITE_IN(stgB);                                      // waits stgB only
    ISSUE_IN(hx + (size_t)row0 * 256 + 128, 256, stgA);  // prefetch chunk 2
    LDS_BARRIER();
    P1STEP(4, br1, br0); P1STEP(5, br2, br1);
    P1STEP(6, br0, br2); P1STEP(7, br1, br0);
    // chunk 2: hx[128:256]
    LDS_BARRIER();
    WRITE_IN(stgA);
    LDS_BARRIER();
    P1STEP(8, br2, br1); P1STEP(9, br0, br2);
    P1STEP(10, br1, br0); P1STEP(11, br2, br1);

    // hoist ts (contiguous 16B-aligned rows)
    v4f tsv4[4];
    #pragma unroll
    for (int mt = 0; mt < 4; ++mt)
        tsv4[mt] = *reinterpret_cast<const v4f*>(
                       &ts[row0 + mt * 16 + ((lane >> 4) << 2)]);

    LDS_BARRIER();                  // all waves done reading last input chunk

    // ------------- activation + write X to LDS in packed A-frag layout ------
    #pragma unroll
    for (int nt = 0; nt < 4; ++nt)
        #pragma unroll
        for (int mt = 0; mt < 4; ++mt)
            #pragma unroll
            for (int r = 0; r < 4; ++r) {
                float xv = 1.7159f * fast_tanh(0.666f * acc[nt][mt][r]);
                int idx = ((mt*8 + w*2 + (nt >> 1)) * 64
                           + ((nt & 1)*2 + ((lane >> 3) & 1)) * 16 + (lane >> 4)*4 + r) * 8
                          + (lane & 7);
                lds[idx] = f2bf(xv);
            }
    LDS_BARRIER();                  // X visible to all waves

    // phase-2 A prologue: load A[ks=0] into afA
    #pragma unroll
    for (int mt = 0; mt < 4; ++mt)
        afA[mt] = *reinterpret_cast<const v8s*>(&lds[((mt * 8 + 0) * 64 + lane) * 8]);

    // ---------------- phase 2: 4 GEMMs over X + fused epilogue --------------
    v4f a2[4][4];
    GINIT(0);
    P2STEP(12,0, br0, br2, afA, afB); P2STEP(13,1, br1, br0, afB, afA);
    P2STEP(14,2, br2, br1, afA, afB); P2STEP(15,3, br0, br2, afB, afA);
    P2STEP(16,4, br1, br0, afA, afB); P2STEP(17,5, br2, br1, afB, afA);
    P2STEP(18,6, br0, br2, afA, afB); P2STEP(19,7, br1, br0, afB, afA);
    EPI(0);
    GINIT(1);
    P2STEP(20,0, br2, br1, afA, afB); P2STEP(21,1, br0, br2, afB, afA);
    P2STEP(22,2, br1, br0, afA, afB); P2STEP(23,3, br2, br1, afB, afA);
    P2STEP(24,4, br0, br2, afA, afB); P2STEP(25,5, br1, br0, afB, afA);
    P2STEP(26,6, br2, br1, afA, afB); P2STEP(27,7, br0, br2, afB, afA);
    EPI(1);
    GINIT(2);
    P2STEP(28,0, br1, br0, afA, afB); P2STEP(29,1, br2, br1, afB, afA);
    P2STEP(30,2, br0, br2, afA, afB); P2STEP(31,3, br1, br0, afB, afA);
    P2STEP(32,4, br2, br1, afA, afB); P2STEP(33,5, br0, br2, afB, afA);
    P2STEP(34,6, br1, br0, afA, afB); P2STEP(35,7, br2, br1, afB, afA);
    EPI(2);
    GINIT(3);
    P2STEP(36,0, br0, br2, afA, afB); P2STEP(37,1, br1, br0, afB, afA);
    P2STEP(38,2, br2, br1, afA, afB); P2STEP(39,3, br0, br2, afB, afA);
    P2STEP(40,4, br1, br0, afA, afB); P2STEP(41,5, br2, br1, afB, afA);
    P2STEP_NS(42,6, br0, afA, afB);   P2STEP_NS(43,7, br1, afB, afA);
    EPI(3);

#undef BLOAD
#undef ISSUE_IN
#undef WRITE_IN
#undef P1STEP
#undef P2STEP
#undef P2STEP_NS
#undef GINIT
#undef EPI
}

extern "C" void kernel_launch(void* const* d_in, const int* in_sizes, int n_in,
                              void* d_out, int out_size, void* d_ws, size_t ws_size,
                              hipStream_t stream)
{
    const float* xin = (const float*)d_in[0];
    const float* hx  = (const float*)d_in[1];
    const float* ts  = (const float*)d_in[2];
    const float* Wb  = (const float*)d_in[3];
    const float* bb  = (const float*)d_in[4];
    const float* W1  = (const float*)d_in[5];
    const float* b1  = (const float*)d_in[6];
    const float* W2  = (const float*)d_in[7];
    const float* b2  = (const float*)d_in[8];
    const float* Wa  = (const float*)d_in[9];
    const float* ba  = (const float*)d_in[10];
    const float* Wt  = (const float*)d_in[11];
    const float* bt  = (const float*)d_in[12];

    if (ws_size < 360448 * sizeof(unsigned short)) return;
    unsigned short* wpk = (unsigned short*)d_ws;

    prep_pack<<<1408, 256, 0, stream>>>(Wb, W1, W2, Wa, Wt, wpk);
    cfc_fused<<<1024, 256, 0, stream>>>(xin, hx, ts, bb, b1, b2, ba, bt, wpk,
                                        (float*)d_out);
}